// Round 3
// baseline (480.314 us; speedup 1.0000x reference)
//
#include <hip/hip_runtime.h>

// QORNN: quantized orthogonal RNN — exact-integer recurrence.
// v6: MFMA offload. Evidence r2/r3: VALUBusy pinned ~57% at BOTH 1 and 2
// waves/SIMD (TLP null -> waves are barrier-phase-locked); sdot count already
// minimal; MfmaUtil = 0. Move z = Wrq.h onto the idle matrix pipe:
//  - v_mfma_i32_16x16x64_i8, A = Wr 16x64 tile (regs), B = h broadcast into
//    all 16 columns (B-frag = ds_read_b128 of h at k-chunk lane>>4 -> frag is
//    lane&15-independent; A/B share the k-mapping so any k-permutation cancels).
//  - 4 row-tiles x 4 chained K-slices = 16 MFMA/wave/step (~75cy matrix pipe)
//    replaces 64 z-sdots (~260cy VALU issue).
//  - lane finalizes output o = ((l&15)>>2)*16 + (l>>4)*4 + (l&3) (bijective),
//    extracted from the replicated C via cndmask selects (no runtime indexing).
//  - u = x.Wi stays on VALU (16 sdots, h-independent, overlaps MFMA).
//  - 256 threads / 4 waves (v5's 8-wave config regressed); modrelu v3-verbatim.

#define TSEQ 1024
#define IDIM 64
#define HDIM 256
#define ODIM 16

using i32x4 = __attribute__((ext_vector_type(4))) int;

__device__ __forceinline__ int sdot4i8(int a, int b, int c) {
#if __has_builtin(__builtin_amdgcn_sdot4)
    return __builtin_amdgcn_sdot4(a, b, c, false);
#else
    int r = c;
    r += ((a << 24) >> 24) * ((b << 24) >> 24);
    r += ((a << 16) >> 24) * ((b << 16) >> 24);
    r += ((a << 8)  >> 24) * ((b << 8)  >> 24);
    r += (a >> 24) * (b >> 24);
    return r;
#endif
}

__device__ __forceinline__ int qpack4(float4 f, float s, float lo, float hi) {
    int a = (int)fminf(fmaxf(rintf(f.x * s), lo), hi);
    int b = (int)fminf(fmaxf(rintf(f.y * s), lo), hi);
    int c = (int)fminf(fmaxf(rintf(f.z * s), lo), hi);
    int d = (int)fminf(fmaxf(rintf(f.w * s), lo), hi);
    return (a & 255) | ((b & 255) << 8) | ((c & 255) << 16) | ((d & 255) << 24);
}

__global__ __launch_bounds__(256, 1)
void qornn_kernel(const float* __restrict__ x, const float* __restrict__ Wi,
                  const float* __restrict__ Wr, const float* __restrict__ Wo,
                  const float* __restrict__ bias, float* __restrict__ out) {
    __shared__ alignas(16) int xlds[TSEQ * 16 + 16]; // whole row, int8-packed (64KB + pad)
    __shared__ alignas(16) int wstage[8192];         // 32 KB staging; Wo resident after init
    __shared__ alignas(16) int hbuf[2][64];          // double-buffered h (256 int8 each)

    const int tid = threadIdx.x;
    const int brow = blockIdx.x;
    const int w   = tid >> 6;           // wave 0..3 -> output rows w*64..w*64+63
    const int l   = tid & 63;
    const int lm  = l & 15;             // MFMA A-row within tile / C column
    const int lg  = l >> 4;             // MFMA K-group / C row-group
    // output this lane finalizes: tile ((l&15)>>2), C-reg (l&3), row-group lg
    const int olocal = ((l & 15) >> 2) * 16 + lg * 4 + (l & 3);
    const int oglob  = w * 64 + olocal;

    // ---- stage Wi [256 x 64] fp32 -> int8 (scale 8); lane keeps full row oglob ----
    {
        const float4* wi4 = (const float4*)Wi;
        #pragma unroll
        for (int it = 0; it < 16; ++it) {
            int flat = it * 256 + tid;
            wstage[flat] = qpack4(wi4[flat], 8.0f, -8.0f, 7.0f);
        }
    }
    __syncthreads();
    int4 wi[4];    // wi[s] = Wi[oglob][s*16 .. s*16+15]
    {
        const int4* p = (const int4*)wstage;
        #pragma unroll
        for (int i = 0; i < 4; ++i) wi[i] = p[oglob * 4 + i];
    }
    __syncthreads();

    // ---- stage Wr [256 x 256] -> int8 in two halves; extract MFMA A-fragments ----
    // wrA[tt][s] = Wr[w*64 + tt*16 + lm][s*64 + lg*16 .. +15]  (16 bytes)
    i32x4 wrA[4][4];
    {
        const float4* wr4 = (const float4*)Wr;
        #pragma unroll
        for (int it = 0; it < 32; ++it) {
            int flat = it * 256 + tid;
            wstage[flat] = qpack4(wr4[flat], 8.0f, -8.0f, 7.0f);
        }
        __syncthreads();
        if (w < 2) {                       // wave-uniform branch
            const i32x4* p = (const i32x4*)wstage;
            #pragma unroll
            for (int tt = 0; tt < 4; ++tt)
                #pragma unroll
                for (int s = 0; s < 4; ++s)
                    wrA[tt][s] = p[(w * 64 + tt * 16 + lm) * 16 + s * 4 + lg];
        }
        __syncthreads();
        #pragma unroll
        for (int it = 0; it < 32; ++it) {
            int flat = it * 256 + tid;
            wstage[flat] = qpack4(wr4[8192 + flat], 8.0f, -8.0f, 7.0f);
        }
        __syncthreads();
        if (w >= 2) {
            const i32x4* p = (const i32x4*)wstage;
            #pragma unroll
            for (int tt = 0; tt < 4; ++tt)
                #pragma unroll
                for (int s = 0; s < 4; ++s)
                    wrA[tt][s] = p[((w - 2) * 64 + tt * 16 + lm) * 16 + s * 4 + lg];
        }
        __syncthreads();
    }

    // ---- stage Wo [16 x 256] -> int8, resident in wstage[0..1023] ----
    {
        const float4* wo4 = (const float4*)Wo;
        #pragma unroll
        for (int it = 0; it < 4; ++it) {
            int flat = it * 256 + tid;
            wstage[flat] = qpack4(wo4[flat], 8.0f, -8.0f, 7.0f);
        }
    }

    // ---- stage entire x row to LDS as int8 (scale 128) ----
    {
        const float4* rowf4 = (const float4*)(x + (size_t)brow * (TSEQ * IDIM));
        #pragma unroll 8
        for (int it = 0; it < 64; ++it) {
            int flat = it * 256 + tid;               // float4 idx == packed dword idx
            xlds[flat] = qpack4(rowf4[flat], 128.0f, -128.0f, 127.0f);
        }
    }
    if (tid < 64) hbuf[0][tid] = 0;                  // h0 = 0
    __syncthreads();

    const float bv = bias[oglob];
    const bool tb1 = (l & 8) != 0;   // tile select bits
    const bool tb0 = (l & 4) != 0;
    const bool rb1 = (l & 2) != 0;   // reg select bits
    const bool rb0 = (l & 1) != 0;

    // u for t=0: full 64-length dot x_0 . Wi[oglob] (uniform broadcast reads)
    int u = 0;
    #pragma unroll
    for (int s = 0; s < 4; ++s) {
        const int4 xx = ((const int4*)xlds)[s];
        u = sdot4i8(xx.x, wi[s].x, u);
        u = sdot4i8(xx.y, wi[s].y, u);
        u = sdot4i8(xx.z, wi[s].z, u);
        u = sdot4i8(xx.w, wi[s].w, u);
    }

    const i32x4 zero4 = {0, 0, 0, 0};

    // ---- main recurrence: 1024 steps, MFMA z + VALU u, 1 barrier/step ----
    #pragma unroll 2
    for (int t = 0; t < TSEQ; ++t) {
        // h_t B-fragments: hB[s] = h[s*64 + lg*16 .. +15] (broadcast per 16-lane group)
        i32x4 hB[4];
        {
            const i32x4* hP = (const i32x4*)hbuf[t & 1];
            #pragma unroll
            for (int s = 0; s < 4; ++s) hB[s] = hP[s * 4 + lg];
        }
        // x_{t+1} (uniform broadcast; xlds padded so t=1023 is safe)
        int4 xn[4];
        #pragma unroll
        for (int s = 0; s < 4; ++s) xn[s] = ((const int4*)xlds)[(t + 1) * 4 + s];

        // z via MFMA: 4 independent row-tiles, each chained over 4 K-slices.
        // B columns all hold h -> every C column replicates z for its 16 rows.
        i32x4 c0 = zero4, c1 = zero4, c2 = zero4, c3 = zero4;
        #pragma unroll
        for (int s = 0; s < 4; ++s) {
            c0 = __builtin_amdgcn_mfma_i32_16x16x64_i8(wrA[0][s], hB[s], c0, 0, 0, 0);
            c1 = __builtin_amdgcn_mfma_i32_16x16x64_i8(wrA[1][s], hB[s], c1, 0, 0, 0);
            c2 = __builtin_amdgcn_mfma_i32_16x16x64_i8(wrA[2][s], hB[s], c2, 0, 0, 0);
            c3 = __builtin_amdgcn_mfma_i32_16x16x64_i8(wrA[3][s], hB[s], c3, 0, 0, 0);
        }

        // u_{t+1} on VALU (h-independent -> overlaps the MFMA chains)
        int un = 0;
        #pragma unroll
        for (int s = 0; s < 4; ++s) {
            un = sdot4i8(xn[s].x, wi[s].x, un);
            un = sdot4i8(xn[s].y, wi[s].y, un);
            un = sdot4i8(xn[s].z, wi[s].z, un);
            un = sdot4i8(xn[s].w, wi[s].w, un);
        }

        // extract this lane's z: tile ((l&15)>>2), reg (l&3) — branchless selects
        const i32x4 ca = tb1 ? c2 : c0;
        const i32x4 cb = tb1 ? c3 : c1;
        const i32x4 ct = tb0 ? cb : ca;
        const int zlo = rb1 ? ct[2] : ct[0];
        const int zhi = rb1 ? ct[3] : ct[1];
        const int z   = (rb0 ? zhi : zlo) + u;

        // exact modrelu + 8-bit requantize (v3 arithmetic, verbatim)
        const float zf = (float)z;
        const float t1 = fmaf(fabsf(zf), 0.0009765625f, bv);
        const float t2 = fmaxf(t1, 0.0f);
        const float r  = rintf(t2 * 128.0f);
        const int vpos = (int)fminf(r, 127.0f);
        const int vneg = -(int)fminf(r, 128.0f);
        int hv = (z < 0) ? vneg : vpos;
        hv = (z == 0) ? 0 : hv;

        ((signed char*)hbuf[(t + 1) & 1])[oglob] = (signed char)hv;

        u = un;
        __syncthreads();
    }

    // ---- epilogue: out[b, o] = h_last . Wo_row(o) / 1024  (h_1024 in hbuf[0]) ----
    if (tid < ODIM) {
        const int4* wo = (const int4*)wstage;
        const int4* hl = (const int4*)hbuf[0];
        int a0 = 0, a1 = 0, a2 = 0, a3 = 0;
        #pragma unroll
        for (int i = 0; i < 16; ++i) {
            int4 w4 = wo[tid * 16 + i];
            int4 h4 = hl[i];
            a0 = sdot4i8(h4.x, w4.x, a0);
            a1 = sdot4i8(h4.y, w4.y, a1);
            a2 = sdot4i8(h4.z, w4.z, a2);
            a3 = sdot4i8(h4.w, w4.w, a3);
        }
        out[brow * ODIM + tid] = (float)((a0 + a1) + (a2 + a3)) * 0.0009765625f;
    }
}

extern "C" void kernel_launch(void* const* d_in, const int* in_sizes, int n_in,
                              void* d_out, int out_size, void* d_ws, size_t ws_size,
                              hipStream_t stream) {
    const float* x  = (const float*)d_in[0];   // [B, T, I]
    const float* Wi = (const float*)d_in[1];   // [H, I]
    const float* Wr = (const float*)d_in[2];   // [H, H]
    const float* Wo = (const float*)d_in[3];   // [O, H]
    const float* b  = (const float*)d_in[4];   // [H]
    float* out = (float*)d_out;                // [B, O]

    const int B = in_sizes[0] / (TSEQ * IDIM); // 256
    qornn_kernel<<<B, HDIM, 0, stream>>>(x, Wi, Wr, Wo, b, out);
}